// Round 4
// baseline (3640.397 us; speedup 1.0000x reference)
//
#include <hip/hip_runtime.h>

typedef unsigned short u16;
typedef __attribute__((ext_vector_type(4))) float f32x4;
typedef __attribute__((ext_vector_type(8))) short s16x8;
typedef __attribute__((ext_vector_type(8))) unsigned short u16x8;

#define NIMG 8
#define HH 100
#define WW 152
#define HP 102
#define WP 154
#define NPIX (NIMG*HH*WW)                       // 121600
#define ACT_ELEMS ((size_t)NIMG*HP*WP*256)      // 32,169,984
#define ACT_BYTES (ACT_ELEMS*2)

__device__ __forceinline__ u16 f2bf(float x){
    unsigned u = __float_as_uint(x);
    unsigned r = (u + 0x7FFFu + ((u >> 16) & 1u)) >> 16;   // RNE
    return (u16)r;
}
__device__ __forceinline__ float bf2f(u16 h){ return __uint_as_float(((unsigned)h) << 16); }

__device__ __forceinline__ void g2l16(const u16* g, u16* l){
    __builtin_amdgcn_global_load_lds((const __attribute__((address_space(1))) unsigned int*)g,
                                     (__attribute__((address_space(3))) unsigned int*)l, 16, 0, 0);
}

// ---------------- border zeroing (pads of both ping-pong activation buffers) ----------------
__global__ void zero_borders(u16* Ah, u16* Al, u16* Bh, u16* Bl){
    int id = blockIdx.x*256 + threadIdx.x;            // 8*508*32 = 130048 exact
    int ch = id & 31; int t = id >> 5;
    int pb = t % 508; int nimg = t / 508;
    int hp, wp;
    if (pb < 154)      { hp = 0;            wp = pb; }
    else if (pb < 308) { hp = 101;          wp = pb - 154; }
    else if (pb < 408) { hp = pb - 308 + 1; wp = 0; }
    else               { hp = pb - 408 + 1; wp = 153; }
    size_t off = ((size_t)((nimg*HP + hp)*WP + wp))*256 + ch*8;
    u16x8 z = {};
    *(u16x8*)(Ah+off) = z; *(u16x8*)(Al+off) = z;
    *(u16x8*)(Bh+off) = z; *(u16x8*)(Bl+off) = z;
}

// ---------------- NCHW fp32 feature -> padded NHWC hi/lo bf16 ----------------
__global__ void feat2act(const float* __restrict__ F, u16* __restrict__ Dh, u16* __restrict__ Dl){
    __shared__ float t[64][65];
    int bid = blockIdx.x;
    int wb = bid % 3; bid /= 3;
    int cb = bid & 3; bid >>= 2;
    int h = bid % 100; int nimg = bid / 100;
    int c0 = cb*64, w0 = wb*64;
    int tid = threadIdx.x;
    int cl = tid >> 6;        // 0..3
    int wl = tid & 63;
    #pragma unroll
    for (int rr=0; rr<16; ++rr){
        int c = rr*4 + cl;
        int w = w0 + wl;
        float v = 0.f;
        if (w < WW) v = F[ ((size_t)((nimg*256 + c0 + c)*HH + h))*WW + w ];
        t[c][wl] = v;
    }
    __syncthreads();
    int wl2 = tid >> 6;
    int cl2 = tid & 63;
    #pragma unroll
    for (int rr=0; rr<16; ++rr){
        int w = rr*4 + wl2;
        if (w0 + w < WW){
            float v = t[cl2][w];
            u16 hb = f2bf(v);
            size_t dst = ((size_t)((nimg*HP + h + 1)*WP + (w0 + w + 1)))*256 + c0 + cl2;
            Dh[dst] = hb;
            Dl[dst] = f2bf(v - bf2f(hb));
        }
    }
}

// ---------------- weight transforms: OIHW fp32 -> [tap][co][ci] hi/lo bf16 ----------------
__global__ void wt_tower(const float* __restrict__ src, u16* __restrict__ dh, u16* __restrict__ dl){
    int idx = blockIdx.x*256 + threadIdx.x;        // layers*9*256*256, exact
    int ci = idx & 255; int t = idx >> 8;
    int co = t & 255; t >>= 8;
    int tap = t % 9; int l = t / 9;
    float v = src[ ((size_t)((l*256+co)*256+ci))*9 + tap ];
    u16 h = f2bf(v);
    dh[idx] = h; dl[idx] = f2bf(v - bf2f(h));
}
__global__ void wt_predctn(const float* __restrict__ pw, const float* __restrict__ cw,
                           u16* __restrict__ dh, u16* __restrict__ dl){
    int idx = blockIdx.x*256 + threadIdx.x;        // 9*128*256 exact
    int ci = idx & 255; int co = (idx>>8) & 127; int tap = idx >> 15;
    float v = 0.f;
    if (co < 64)       v = pw[ ((size_t)(co*256+ci))*9 + tap ];
    else if (co == 64) v = cw[ (size_t)ci*9 + tap ];
    u16 h = f2bf(v);
    dh[idx] = h; dl[idx] = f2bf(v - bf2f(h));
}
__global__ void wt_score(const float* __restrict__ sw, u16* __restrict__ dh, u16* __restrict__ dl){
    int idx = blockIdx.x*256 + threadIdx.x;
    int ci = idx & 255; int co = (idx>>8) & 127; int tap = idx >> 15;
    float v = (co == 0) ? sw[ (size_t)ci*9 + tap ] : 0.f;
    u16 h = f2bf(v);
    dh[idx] = h; dl[idx] = f2bf(v - bf2f(h));
}
__global__ void prep_bias(const float* pb, const float* cb, const float* sb, float* bpc, float* bsc){
    int i = threadIdx.x;      // 128
    bpc[i] = (i < 64) ? pb[i] : ((i == 64) ? cb[0] : 0.f);
    bsc[i] = (i == 0) ? sb[0] : 0.f;
}

// ---------------- conv3x3 implicit GEMM, split-bf16 (3 MFMA), 128x128 tile ----------------
// Counted-vmcnt pipeline (T3+T4): depth-2 prefetch, 2 LDS buffers, raw s_barrier,
// per-step: ds_read -> lgkmcnt(0) -> bar -> stage(t+2,same buf) -> MFMA -> vmcnt(8) -> bar.
// vmcnt(8) leaves stage(t+2)'s 8 loads in flight across the barrier (never drain to 0 mid-loop).
// MODE 0: tower (relu, store padded NHWC hi/lo)
// MODE 1: pred+ctn head (fp32, co<64 -> O1[pix*64+co], co==64 -> O2[pix])
// MODE 2: score head (fp32, co==0 -> O1[pix])
template<int MODE>
__global__ __launch_bounds__(256, 2) void conv3x3_k(
    const u16* __restrict__ Ah, const u16* __restrict__ Al,
    const u16* __restrict__ Wh, const u16* __restrict__ Wl,
    const float* __restrict__ bias,
    u16* __restrict__ Oh, u16* __restrict__ Ol,
    float* __restrict__ O1, float* __restrict__ O2,
    int NB, int COUTP)
{
    // per buffer (u16 units): A_hi[128][32]@0, A_lo@4096, B_hi@8192, B_lo@12288 ; buf1 at +16384
    __shared__ u16 lds[32768];   // 64 KiB
    const int tid  = threadIdx.x;
    const int lane = tid & 63;
    const int wave = tid >> 6;

    // bijective XCD swizzle (gridDim.x % 8 == 0)
    int nwg = gridDim.x;
    int bid = blockIdx.x;
    int qq  = nwg >> 3;
    int swz = (bid & 7)*qq + (bid >> 3);
    int nblk = swz % NB;
    int mblk = swz / NB;
    int nimg = mblk / 125;
    int rem  = mblk - nimg*125;
    int ht   = rem / 5;
    int wt5  = rem - ht*5;
    int h0 = ht*4, w0 = wt5*32;
    int co0 = nblk*128;

    // staging source offsets (elements). slot s: p=s>>2 row, ch=s&3 16B chunk.
    // pre-swizzled source chunk: chs = ch ^ ((p>>1)&3)  (involution, matches read side)
    int aoff[2], boff[2];
    #pragma unroll
    for (int it=0; it<2; ++it){
        int s = it*256 + tid;
        int p = s >> 2, ch = s & 3;
        int chs = ch ^ ((p >> 1) & 3);
        int i = p >> 5, j = p & 31;
        aoff[it] = ((nimg*HP + h0 + i)*WP + (w0 + j))*256 + chs*8;
        boff[it] = (co0 + p)*256 + chs*8;
    }
    const int ldst = wave*512;   // wave-uniform LDS dest (ushort units), + it*2048

    // fragment-read lane constants (swizzled read chunk)
    const int r    = lane & 15;
    const int q4   = lane >> 4;
    const int chrd = (q4 ^ ((r >> 1) & 3)) * 8;
    const int wm = wave >> 1, wn = wave & 1;
    const int aBase = (wm*64 + r)*32 + chrd;
    const int bBase = 8192 + (wn*64 + r)*32 + chrd;

    f32x4 acc[4][4];
    #pragma unroll
    for (int m=0;m<4;m++)
        #pragma unroll
        for (int n=0;n<4;n++)
            acc[m][n] = (f32x4)0.0f;

    auto stage = [&](int t, int b){
        int tap = t >> 3, kb = t & 7;
        int kh = tap/3, kw = tap - kh*3;
        int adel = (kh*WP + kw)*256 + kb*32;
        int bdel = tap*COUTP*256 + kb*32;
        u16* L = lds + b*16384;
        #pragma unroll
        for (int it=0; it<2; ++it){
            g2l16(Ah + aoff[it] + adel, L +         it*2048 + ldst);
            g2l16(Al + aoff[it] + adel, L +  4096 + it*2048 + ldst);
        }
        #pragma unroll
        for (int it=0; it<2; ++it){
            g2l16(Wh + boff[it] + bdel, L +  8192 + it*2048 + ldst);
            g2l16(Wl + boff[it] + bdel, L + 12288 + it*2048 + ldst);
        }
    };

    // prologue: prime both buffers; wait only for buf0 (buf1's 8 loads stay in flight)
    stage(0, 0);
    stage(1, 1);
    asm volatile("s_waitcnt vmcnt(8)" ::: "memory");
    __builtin_amdgcn_s_barrier();

    for (int t=0; t<72; ++t){
        int b = t & 1;
        const u16* L = lds + b*16384;
        s16x8 ahf[4], alf[4], bhf[4], blf[4];
        #pragma unroll
        for (int m=0;m<4;m++){
            ahf[m] = *(const s16x8*)(L +        aBase + m*512);
            alf[m] = *(const s16x8*)(L + 4096 + aBase + m*512);
            bhf[m] = *(const s16x8*)(L +        bBase + m*512);
            blf[m] = *(const s16x8*)(L + 4096 + bBase + m*512);
        }
        asm volatile("s_waitcnt lgkmcnt(0)" ::: "memory");   // all my reads of buf[b] drained
        __builtin_amdgcn_s_barrier();                        // ALL waves done reading buf[b]
        __builtin_amdgcn_sched_barrier(0);
        if (t < 70) stage(t+2, b);                           // WAR-safe overwrite of buf[b]
        __builtin_amdgcn_s_setprio(1);
        #pragma unroll
        for (int n=0;n<4;n++){
            #pragma unroll
            for (int m=0;m<4;m++){
                acc[m][n] = __builtin_amdgcn_mfma_f32_16x16x32_bf16(ahf[m], bhf[n], acc[m][n], 0,0,0);
                acc[m][n] = __builtin_amdgcn_mfma_f32_16x16x32_bf16(ahf[m], blf[n], acc[m][n], 0,0,0);
                acc[m][n] = __builtin_amdgcn_mfma_f32_16x16x32_bf16(alf[m], bhf[n], acc[m][n], 0,0,0);
            }
        }
        __builtin_amdgcn_s_setprio(0);
        __builtin_amdgcn_sched_barrier(0);
        if (t < 70) { asm volatile("s_waitcnt vmcnt(8)" ::: "memory"); }  // stage(t+1) landed; stage(t+2) in flight
        else        { asm volatile("s_waitcnt vmcnt(0)" ::: "memory"); }
        __builtin_amdgcn_s_barrier();                        // buf[b^1] staged for all waves
    }

    float bcol[4];
    #pragma unroll
    for (int n=0;n<4;n++) bcol[n] = bias[co0 + wn*64 + n*16 + r];

    if (MODE == 0){
        // hi pass through LDS repack -> 16B contiguous stores
        #pragma unroll
        for (int m=0;m<4;m++)
            #pragma unroll
            for (int n=0;n<4;n++)
                #pragma unroll
                for (int jj=0;jj<4;jj++){
                    float v = fmaxf(acc[m][n][jj] + bcol[n], 0.f);
                    int p = wm*64 + m*16 + q4*4 + jj;
                    int c = wn*64 + n*16 + r;
                    lds[p*128 + c] = f2bf(v);
                }
        __syncthreads();
        #pragma unroll
        for (int it=0; it<8; ++it){
            int s = it*256 + tid;
            int p = s >> 4, chh = s & 15;
            int i = p >> 5, j = p & 31;
            if (w0 + j < WW){
                size_t dst = ((size_t)((nimg*HP + h0 + i + 1)*WP + (w0 + j + 1)))*256 + co0 + chh*8;
                *(u16x8*)(Oh + dst) = *(const u16x8*)(lds + p*128 + chh*8);
            }
        }
        __syncthreads();
        #pragma unroll
        for (int m=0;m<4;m++)
            #pragma unroll
            for (int n=0;n<4;n++)
                #pragma unroll
                for (int jj=0;jj<4;jj++){
                    float v = fmaxf(acc[m][n][jj] + bcol[n], 0.f);
                    int p = wm*64 + m*16 + q4*4 + jj;
                    int c = wn*64 + n*16 + r;
                    u16 hb = f2bf(v);
                    lds[p*128 + c] = f2bf(v - bf2f(hb));
                }
        __syncthreads();
        #pragma unroll
        for (int it=0; it<8; ++it){
            int s = it*256 + tid;
            int p = s >> 4, chh = s & 15;
            int i = p >> 5, j = p & 31;
            if (w0 + j < WW){
                size_t dst = ((size_t)((nimg*HP + h0 + i + 1)*WP + (w0 + j + 1)))*256 + co0 + chh*8;
                *(u16x8*)(Ol + dst) = *(const u16x8*)(lds + p*128 + chh*8);
            }
        }
    } else {
        #pragma unroll
        for (int m=0;m<4;m++)
            #pragma unroll
            for (int n=0;n<4;n++)
                #pragma unroll
                for (int jj=0;jj<4;jj++){
                    float v = acc[m][n][jj] + bcol[n];
                    int p = wm*64 + m*16 + q4*4 + jj;
                    int c = co0 + wn*64 + n*16 + r;
                    int i = p >> 5, j = p & 31;
                    if (w0 + j < WW){
                        int pix = nimg*(HH*WW) + (h0+i)*WW + (w0+j);
                        if (MODE == 1){
                            if (c < 64)       O1[(size_t)pix*64 + c] = v;
                            else if (c == 64) O2[pix] = v;
                        } else {
                            if (c == 0) O1[pix] = v;
                        }
                    }
                }
    }
}

// ---------------- fused stat (softmax / erf-pmf / top4) + conf 1x1 convs + sigmoid*sigmoid ----------------
__global__ __launch_bounds__(256) void fuse_stat(
    const float* __restrict__ bbox, const float* __restrict__ cls_score,
    const float* __restrict__ w1, const float* __restrict__ b1,
    const float* __restrict__ w2, const float* __restrict__ b2,
    float* __restrict__ pred_cls)
{
    __shared__ float sstat[48][256];
    int tid = threadIdx.x;
    int pix = blockIdx.x*256 + tid;
    if (pix >= NPIX) return;
    const f32x4* row4 = (const f32x4*)(bbox + (size_t)pix*64);
    for (int g=0; g<4; ++g){
        f32x4 v0 = row4[g*4+0], v1 = row4[g*4+1], v2 = row4[g*4+2], v3 = row4[g*4+3];
        float lg[8], ls[8];
        #pragma unroll
        for (int k=0;k<4;k++){ lg[k]=v0[k]; lg[4+k]=v1[k]; ls[k]=v2[k]; ls[4+k]=v3[k]; }
        float m = lg[0];
        #pragma unroll
        for (int k=1;k<8;k++) m = fmaxf(m, lg[k]);
        float e[8], s = 0.f;
        #pragma unroll
        for (int k=0;k<8;k++){ e[k] = expf(lg[k]-m); s += e[k]; }
        float isum = 1.0f/s;
        float prob[8];
        #pragma unroll
        for (int k=0;k<8;k++) prob[k] = e[k]*isum;
        float pmf[8];
        #pragma unroll
        for (int k=0;k<8;k++) pmf[k] = 0.f;
        #pragma unroll
        for (int i=0;i<8;i++){
            float invi = 1.0f/(expf(ls[i]) * 1.41421356237309515f);
            float pi = prob[i];
            #pragma unroll
            for (int j=0;j<8;j++){
                float d = (float)(j - i);
                pmf[j] = fmaf(0.5f*(erff((d+1.0f)*invi) - erff((d-1.0f)*invi)), pi, pmf[j]);
            }
        }
        int used = 0;
        #pragma unroll
        for (int t=0;t<4;t++){
            float bv = -3.0e38f; int bi = 0;
            #pragma unroll
            for (int j=0;j<8;j++){
                bool ok = (((used>>j)&1)==0) && (pmf[j] > bv);
                bv = ok ? pmf[j] : bv;
                bi = ok ? j : bi;
            }
            used |= (1<<bi);
            float sl=0.f, sp=0.f;
            #pragma unroll
            for (int j=0;j<8;j++){ if (j==bi){ sl=ls[j]; sp=prob[j]; } }
            sstat[g*4+t][tid]    = sl;
            sstat[16+g*4+t][tid] = sp;
            sstat[32+g*4+t][tid] = bv;
        }
    }
    float q = b2[0];
    for (int u=0; u<64; ++u){
        float h = b1[u];
        #pragma unroll
        for (int c=0;c<48;c++) h = fmaf(sstat[c][tid], w1[u*48+c], h);
        q = fmaf(fmaxf(h,0.f), w2[u], q);
    }
    float quality = 1.0f/(1.0f+expf(-q));
    float cs = cls_score[pix];
    pred_cls[pix] = quality/(1.0f+expf(-cs));
}

// ---------------- launch ----------------
extern "C" void kernel_launch(void* const* d_in, const int* in_sizes, int n_in,
                              void* d_out, int out_size, void* d_ws, size_t ws_size,
                              hipStream_t stream) {
    (void)in_sizes; (void)n_in; (void)out_size;
    const float* feature = (const float*)d_in[0];
    const float* cls_w   = (const float*)d_in[1];
    const float* cls_b   = (const float*)d_in[2];
    const float* box_w   = (const float*)d_in[3];
    const float* box_b   = (const float*)d_in[4];
    const float* score_w = (const float*)d_in[5];
    const float* score_b = (const float*)d_in[6];
    const float* pred_w  = (const float*)d_in[7];
    const float* pred_b  = (const float*)d_in[8];
    const float* ctn_w   = (const float*)d_in[9];
    const float* ctn_b   = (const float*)d_in[10];
    const float* conf_w1 = (const float*)d_in[11];
    const float* conf_b1 = (const float*)d_in[12];
    const float* conf_w2 = (const float*)d_in[13];
    const float* conf_b2 = (const float*)d_in[14];

    float* out      = (float*)d_out;
    float* pred_cls = out;
    float* pred_reg = out + NPIX;
    float* pred_ctn = out + NPIX + (size_t)NPIX*64;

    char* ws = (char*)d_ws;
    size_t off = 0;
    auto alloc = [&](size_t b){ size_t rr = off; off += (b + 255) & ~(size_t)255; return rr; };
    u16* aAh = (u16*)(ws + alloc(ACT_BYTES));
    u16* aAl = (u16*)(ws + alloc(ACT_BYTES));
    u16* aBh = (u16*)(ws + alloc(ACT_BYTES));
    u16* aBl = (u16*)(ws + alloc(ACT_BYTES));
    const size_t TWR = (size_t)4*9*256*256;   // tower wt elements
    const size_t HDW = (size_t)9*128*256;     // head wt elements
    u16* wClsH = (u16*)(ws + alloc(TWR*2));
    u16* wClsL = (u16*)(ws + alloc(TWR*2));
    u16* wBoxH = (u16*)(ws + alloc(TWR*2));
    u16* wBoxL = (u16*)(ws + alloc(TWR*2));
    u16* wScH  = (u16*)(ws + alloc(HDW*2));
    u16* wScL  = (u16*)(ws + alloc(HDW*2));
    u16* wPcH  = (u16*)(ws + alloc(HDW*2));
    u16* wPcL  = (u16*)(ws + alloc(HDW*2));
    float* bPc = (float*)(ws + alloc(128*4));
    float* bSc = (float*)(ws + alloc(128*4));
    float* clsScore = (float*)(ws + alloc((size_t)NPIX*4));
    if (ws_size < off) return;   // insufficient workspace: bail (bench will flag)

    dim3 B(256);
    // prep
    zero_borders<<<508, B, 0, stream>>>(aAh, aAl, aBh, aBl);
    wt_tower<<<9216, B, 0, stream>>>(cls_w, wClsH, wClsL);
    wt_tower<<<9216, B, 0, stream>>>(box_w, wBoxH, wBoxL);
    wt_score<<<1152, B, 0, stream>>>(score_w, wScH, wScL);
    wt_predctn<<<1152, B, 0, stream>>>(pred_w, ctn_w, wPcH, wPcL);
    prep_bias<<<1, 128, 0, stream>>>(pred_b, ctn_b, score_b, bPc, bSc);

    const size_t LW = (size_t)9*256*256;      // per-layer tower wt elements
    // cls tower: feat->A, A->B->A->B->A  (B's feature copy is clobbered by layer 1,
    // so the box tower re-materializes its own input below — do NOT share)
    feat2act<<<9600, B, 0, stream>>>(feature, aAh, aAl);
    conv3x3_k<0><<<2000, B, 0, stream>>>(aAh, aAl, wClsH+0*LW, wClsL+0*LW, cls_b+0*256, aBh, aBl, nullptr, nullptr, 2, 256);
    conv3x3_k<0><<<2000, B, 0, stream>>>(aBh, aBl, wClsH+1*LW, wClsL+1*LW, cls_b+1*256, aAh, aAl, nullptr, nullptr, 2, 256);
    conv3x3_k<0><<<2000, B, 0, stream>>>(aAh, aAl, wClsH+2*LW, wClsL+2*LW, cls_b+2*256, aBh, aBl, nullptr, nullptr, 2, 256);
    conv3x3_k<0><<<2000, B, 0, stream>>>(aBh, aBl, wClsH+3*LW, wClsL+3*LW, cls_b+3*256, aAh, aAl, nullptr, nullptr, 2, 256);
    // score head (reads x4 in A)
    conv3x3_k<2><<<1000, B, 0, stream>>>(aAh, aAl, wScH, wScL, bSc, nullptr, nullptr, clsScore, nullptr, 1, 128);
    // box tower: feat->B, B->A->B->A->B
    feat2act<<<9600, B, 0, stream>>>(feature, aBh, aBl);
    conv3x3_k<0><<<2000, B, 0, stream>>>(aBh, aBl, wBoxH+0*LW, wBoxL+0*LW, box_b+0*256, aAh, aAl, nullptr, nullptr, 2, 256);
    conv3x3_k<0><<<2000, B, 0, stream>>>(aAh, aAl, wBoxH+1*LW, wBoxL+1*LW, box_b+1*256, aBh, aBl, nullptr, nullptr, 2, 256);
    conv3x3_k<0><<<2000, B, 0, stream>>>(aBh, aBl, wBoxH+2*LW, wBoxL+2*LW, box_b+2*256, aAh, aAl, nullptr, nullptr, 2, 256);
    conv3x3_k<0><<<2000, B, 0, stream>>>(aAh, aAl, wBoxH+3*LW, wBoxL+3*LW, box_b+3*256, aBh, aBl, nullptr, nullptr, 2, 256);
    // pred + ctn head (reads y4 in B) -> writes pred_reg / pred_ctn directly
    conv3x3_k<1><<<1000, B, 0, stream>>>(aBh, aBl, wPcH, wPcL, bPc, nullptr, nullptr, pred_reg, pred_ctn, 1, 128);
    // fused stat + conf + final cls
    fuse_stat<<<475, B, 0, stream>>>(pred_reg, clsScore, conf_w1, conf_b1, conf_w2, conf_b2, pred_cls);
}

// Round 5
// 1419.852 us; speedup vs baseline: 2.5639x; 2.5639x over previous
//
#include <hip/hip_runtime.h>

typedef unsigned short u16;
typedef _Float16 f16;
typedef __attribute__((ext_vector_type(4))) float f32x4;
typedef __attribute__((ext_vector_type(8))) _Float16 f16x8;
typedef __attribute__((ext_vector_type(8))) unsigned short u16x8;

#define NIMG 8
#define HH 100
#define WW 152
#define HP 102
#define WP 154
#define NPIX (NIMG*HH*WW)                       // 121600
#define ACT_ELEMS ((size_t)NIMG*HP*WP*256)      // 32,169,984
#define ACT_BYTES (ACT_ELEMS*2)

__device__ __forceinline__ u16 f2h(float x){
    f16 h = (f16)x;                       // v_cvt_f16_f32, RNE
    return __builtin_bit_cast(u16, h);
}

__device__ __forceinline__ void g2l16(const u16* g, u16* l){
    __builtin_amdgcn_global_load_lds((const __attribute__((address_space(1))) unsigned int*)g,
                                     (__attribute__((address_space(3))) unsigned int*)l, 16, 0, 0);
}

// ---------------- border zeroing (pads of both ping-pong activation buffers) ----------------
__global__ void zero_borders(u16* A, u16* B){
    int id = blockIdx.x*256 + threadIdx.x;            // 8*508*32 = 130048 exact
    int ch = id & 31; int t = id >> 5;
    int pb = t % 508; int nimg = t / 508;
    int hp, wp;
    if (pb < 154)      { hp = 0;            wp = pb; }
    else if (pb < 308) { hp = 101;          wp = pb - 154; }
    else if (pb < 408) { hp = pb - 308 + 1; wp = 0; }
    else               { hp = pb - 408 + 1; wp = 153; }
    size_t off = ((size_t)((nimg*HP + hp)*WP + wp))*256 + ch*8;
    u16x8 z = {};
    *(u16x8*)(A+off) = z; *(u16x8*)(B+off) = z;
}

// ---------------- NCHW fp32 feature -> padded NHWC fp16 ----------------
__global__ void feat2act(const float* __restrict__ F, u16* __restrict__ D){
    __shared__ float t[64][65];
    int bid = blockIdx.x;
    int wb = bid % 3; bid /= 3;
    int cb = bid & 3; bid >>= 2;
    int h = bid % 100; int nimg = bid / 100;
    int c0 = cb*64, w0 = wb*64;
    int tid = threadIdx.x;
    int cl = tid >> 6;        // 0..3
    int wl = tid & 63;
    #pragma unroll
    for (int rr=0; rr<16; ++rr){
        int c = rr*4 + cl;
        int w = w0 + wl;
        float v = 0.f;
        if (w < WW) v = F[ ((size_t)((nimg*256 + c0 + c)*HH + h))*WW + w ];
        t[c][wl] = v;
    }
    __syncthreads();
    int wl2 = tid >> 6;
    int cl2 = tid & 63;
    #pragma unroll
    for (int rr=0; rr<16; ++rr){
        int w = rr*4 + wl2;
        if (w0 + w < WW){
            size_t dst = ((size_t)((nimg*HP + h + 1)*WP + (w0 + w + 1)))*256 + c0 + cl2;
            D[dst] = f2h(t[cl2][w]);
        }
    }
}

// ---------------- weight transforms: OIHW fp32 -> [tap][co][ci] fp16 ----------------
__global__ void wt_tower(const float* __restrict__ src, u16* __restrict__ d){
    int idx = blockIdx.x*256 + threadIdx.x;        // layers*9*256*256, exact
    int ci = idx & 255; int t = idx >> 8;
    int co = t & 255; t >>= 8;
    int tap = t % 9; int l = t / 9;
    d[idx] = f2h(src[ ((size_t)((l*256+co)*256+ci))*9 + tap ]);
}
__global__ void wt_predctn(const float* __restrict__ pw, const float* __restrict__ cw,
                           u16* __restrict__ d){
    int idx = blockIdx.x*256 + threadIdx.x;        // 9*128*256 exact
    int ci = idx & 255; int co = (idx>>8) & 127; int tap = idx >> 15;
    float v = 0.f;
    if (co < 64)       v = pw[ ((size_t)(co*256+ci))*9 + tap ];
    else if (co == 64) v = cw[ (size_t)ci*9 + tap ];
    d[idx] = f2h(v);
}
__global__ void wt_score(const float* __restrict__ sw, u16* __restrict__ d){
    int idx = blockIdx.x*256 + threadIdx.x;
    int ci = idx & 255; int co = (idx>>8) & 127; int tap = idx >> 15;
    d[idx] = f2h((co == 0) ? sw[ (size_t)ci*9 + tap ] : 0.f);
}
__global__ void prep_bias(const float* pb, const float* cb, const float* sb, float* bpc, float* bsc){
    int i = threadIdx.x;      // 128
    bpc[i] = (i < 64) ? pb[i] : ((i == 64) ? cb[0] : 0.f);
    bsc[i] = (i == 0) ? sb[0] : 0.f;
}

// ---------------- conv3x3 implicit GEMM, fp16 single-pass, 128x128 tile, BK=64 ----------------
// Counted-vmcnt pipeline (T3+T4): depth-2 prefetch, 2 LDS buffers, raw s_barrier,
// per-step: ds_read -> lgkmcnt(0) -> bar -> stage(t+2,same buf) -> MFMA -> vmcnt(8) -> bar.
// LDS tile per buffer: A[128 rows][64 k] fp16 @0 (16 KB), B[128 co][64 k] @8192 u16; buf stride 16384 u16.
// Swizzle: 16B chunk index (8/row) XOR'd with (row&7) on BOTH stage-source and read side.
// MODE 0: tower (relu, store padded NHWC fp16)
// MODE 1: pred+ctn head (fp32, co<64 -> O1[pix*64+co], co==64 -> O2[pix])
// MODE 2: score head (fp32, co==0 -> O1[pix])
template<int MODE>
__global__ __launch_bounds__(256, 2) void conv3x3_k(
    const u16* __restrict__ Ah, const u16* __restrict__ Wh,
    const float* __restrict__ bias,
    u16* __restrict__ Oh,
    float* __restrict__ O1, float* __restrict__ O2,
    int NB, int COUTP)
{
    __shared__ u16 lds[32768];   // 64 KiB (2 buffers)
    const int tid  = threadIdx.x;
    const int lane = tid & 63;
    const int wave = tid >> 6;

    // bijective XCD swizzle (gridDim.x % 8 == 0)
    int nwg = gridDim.x;
    int bid = blockIdx.x;
    int qq  = nwg >> 3;
    int swz = (bid & 7)*qq + (bid >> 3);
    int nblk = swz % NB;
    int mblk = swz / NB;
    int nimg = mblk / 125;
    int rem  = mblk - nimg*125;
    int ht   = rem / 5;
    int wt5  = rem - ht*5;
    int h0 = ht*4, w0 = wt5*32;
    int co0 = nblk*128;

    // staging source offsets. slot s: p=s>>3 row, ch=s&7 16B chunk; chs = ch ^ (p&7).
    int aoff[4], boff[4];
    #pragma unroll
    for (int it=0; it<4; ++it){
        int s = it*256 + tid;
        int p = s >> 3, ch = s & 7;
        int chs = ch ^ (p & 7);
        int i = p >> 5, j = p & 31;
        aoff[it] = ((nimg*HP + h0 + i)*WP + (w0 + j))*256 + chs*8;
        boff[it] = (co0 + p)*256 + chs*8;
    }
    const int ldst = wave*512;   // wave-uniform LDS dest (u16), + it*2048

    // fragment-read lane constants
    const int r  = lane & 15;
    const int q4 = lane >> 4;
    const int c0k = ((q4    ) ^ (r & 7)) * 8;   // k-chunk for kk=0
    const int c1k = ((q4 + 4) ^ (r & 7)) * 8;   // k-chunk for kk=1
    const int wm = wave >> 1, wn = wave & 1;
    const int aBase = (wm*64 + r)*64;
    const int bBase = 8192 + (wn*64 + r)*64;

    f32x4 acc[4][4];
    #pragma unroll
    for (int m=0;m<4;m++)
        #pragma unroll
        for (int n=0;n<4;n++)
            acc[m][n] = (f32x4)0.0f;

    auto stage = [&](int t, int b){
        int tap = t >> 2, kb = t & 3;
        int kh = tap/3, kw = tap - kh*3;
        int adel = (kh*WP + kw)*256 + kb*64;
        int bdel = tap*COUTP*256 + kb*64;
        u16* L = lds + b*16384;
        #pragma unroll
        for (int it=0; it<4; ++it)
            g2l16(Ah + aoff[it] + adel, L +        it*2048 + ldst);
        #pragma unroll
        for (int it=0; it<4; ++it)
            g2l16(Wh + boff[it] + bdel, L + 8192 + it*2048 + ldst);
    };

    // prologue: prime both buffers; wait only for buf0 (buf1's 8 loads stay in flight)
    stage(0, 0);
    stage(1, 1);
    asm volatile("s_waitcnt vmcnt(8)" ::: "memory");
    __builtin_amdgcn_s_barrier();

    for (int t=0; t<36; ++t){
        int b = t & 1;
        const u16* L = lds + b*16384;
        f16x8 a0[4], a1[4], b0[4], b1[4];
        #pragma unroll
        for (int m=0;m<4;m++){
            a0[m] = *(const f16x8*)(L + aBase + m*1024 + c0k);
            a1[m] = *(const f16x8*)(L + aBase + m*1024 + c1k);
            b0[m] = *(const f16x8*)(L + bBase + m*1024 + c0k);
            b1[m] = *(const f16x8*)(L + bBase + m*1024 + c1k);
        }
        asm volatile("s_waitcnt lgkmcnt(0)" ::: "memory");   // my reads of buf[b] drained
        __builtin_amdgcn_s_barrier();                        // ALL waves done reading buf[b]
        __builtin_amdgcn_sched_barrier(0);
        if (t < 34) stage(t+2, b);                           // WAR-safe overwrite of buf[b]
        __builtin_amdgcn_s_setprio(1);
        #pragma unroll
        for (int n=0;n<4;n++){
            #pragma unroll
            for (int m=0;m<4;m++){
                acc[m][n] = __builtin_amdgcn_mfma_f32_16x16x32_f16(a0[m], b0[n], acc[m][n], 0,0,0);
                acc[m][n] = __builtin_amdgcn_mfma_f32_16x16x32_f16(a1[m], b1[n], acc[m][n], 0,0,0);
            }
        }
        __builtin_amdgcn_s_setprio(0);
        __builtin_amdgcn_sched_barrier(0);
        if (t < 34) { asm volatile("s_waitcnt vmcnt(8)" ::: "memory"); }  // stage(t+1) landed
        else        { asm volatile("s_waitcnt vmcnt(0)" ::: "memory"); }
        __builtin_amdgcn_s_barrier();                        // buf[b^1] staged for all waves
    }

    float bcol[4];
    #pragma unroll
    for (int n=0;n<4;n++) bcol[n] = bias[co0 + wn*64 + n*16 + r];

    if (MODE == 0){
        // acc -> fp16 via LDS repack -> 16B contiguous stores
        #pragma unroll
        for (int m=0;m<4;m++)
            #pragma unroll
            for (int n=0;n<4;n++)
                #pragma unroll
                for (int jj=0;jj<4;jj++){
                    float v = fmaxf(acc[m][n][jj] + bcol[n], 0.f);
                    int p = wm*64 + m*16 + q4*4 + jj;
                    int c = wn*64 + n*16 + r;
                    lds[p*128 + c] = f2h(v);
                }
        __syncthreads();
        #pragma unroll
        for (int it=0; it<8; ++it){
            int s = it*256 + tid;
            int p = s >> 4, chh = s & 15;
            int i = p >> 5, j = p & 31;
            if (w0 + j < WW){
                size_t dst = ((size_t)((nimg*HP + h0 + i + 1)*WP + (w0 + j + 1)))*256 + co0 + chh*8;
                *(u16x8*)(Oh + dst) = *(const u16x8*)(lds + p*128 + chh*8);
            }
        }
    } else {
        #pragma unroll
        for (int m=0;m<4;m++)
            #pragma unroll
            for (int n=0;n<4;n++)
                #pragma unroll
                for (int jj=0;jj<4;jj++){
                    float v = acc[m][n][jj] + bcol[n];
                    int p = wm*64 + m*16 + q4*4 + jj;
                    int c = co0 + wn*64 + n*16 + r;
                    int i = p >> 5, j = p & 31;
                    if (w0 + j < WW){
                        int pix = nimg*(HH*WW) + (h0+i)*WW + (w0+j);
                        if (MODE == 1){
                            if (c < 64)       O1[(size_t)pix*64 + c] = v;
                            else if (c == 64) O2[pix] = v;
                        } else {
                            if (c == 0) O1[pix] = v;
                        }
                    }
                }
    }
}

// ---------------- fused stat (softmax / erf-pmf / top4) + conf 1x1 convs + sigmoid*sigmoid ----------------
__global__ __launch_bounds__(256) void fuse_stat(
    const float* __restrict__ bbox, const float* __restrict__ cls_score,
    const float* __restrict__ w1, const float* __restrict__ b1,
    const float* __restrict__ w2, const float* __restrict__ b2,
    float* __restrict__ pred_cls)
{
    __shared__ float sstat[48][256];
    int tid = threadIdx.x;
    int pix = blockIdx.x*256 + tid;
    if (pix >= NPIX) return;
    const f32x4* row4 = (const f32x4*)(bbox + (size_t)pix*64);
    for (int g=0; g<4; ++g){
        f32x4 v0 = row4[g*4+0], v1 = row4[g*4+1], v2 = row4[g*4+2], v3 = row4[g*4+3];
        float lg[8], ls[8];
        #pragma unroll
        for (int k=0;k<4;k++){ lg[k]=v0[k]; lg[4+k]=v1[k]; ls[k]=v2[k]; ls[4+k]=v3[k]; }
        float m = lg[0];
        #pragma unroll
        for (int k=1;k<8;k++) m = fmaxf(m, lg[k]);
        float e[8], s = 0.f;
        #pragma unroll
        for (int k=0;k<8;k++){ e[k] = expf(lg[k]-m); s += e[k]; }
        float isum = 1.0f/s;
        float prob[8];
        #pragma unroll
        for (int k=0;k<8;k++) prob[k] = e[k]*isum;
        float pmf[8];
        #pragma unroll
        for (int k=0;k<8;k++) pmf[k] = 0.f;
        #pragma unroll
        for (int i=0;i<8;i++){
            float invi = 1.0f/(expf(ls[i]) * 1.41421356237309515f);
            float pi = prob[i];
            #pragma unroll
            for (int j=0;j<8;j++){
                float d = (float)(j - i);
                pmf[j] = fmaf(0.5f*(erff((d+1.0f)*invi) - erff((d-1.0f)*invi)), pi, pmf[j]);
            }
        }
        int used = 0;
        #pragma unroll
        for (int t=0;t<4;t++){
            float bv = -3.0e38f; int bi = 0;
            #pragma unroll
            for (int j=0;j<8;j++){
                bool ok = (((used>>j)&1)==0) && (pmf[j] > bv);
                bv = ok ? pmf[j] : bv;
                bi = ok ? j : bi;
            }
            used |= (1<<bi);
            float sl=0.f, sp=0.f;
            #pragma unroll
            for (int j=0;j<8;j++){ if (j==bi){ sl=ls[j]; sp=prob[j]; } }
            sstat[g*4+t][tid]    = sl;
            sstat[16+g*4+t][tid] = sp;
            sstat[32+g*4+t][tid] = bv;
        }
    }
    float q = b2[0];
    for (int u=0; u<64; ++u){
        float h = b1[u];
        #pragma unroll
        for (int c=0;c<48;c++) h = fmaf(sstat[c][tid], w1[u*48+c], h);
        q = fmaf(fmaxf(h,0.f), w2[u], q);
    }
    float quality = 1.0f/(1.0f+expf(-q));
    float cs = cls_score[pix];
    pred_cls[pix] = quality/(1.0f+expf(-cs));
}

// ---------------- launch ----------------
extern "C" void kernel_launch(void* const* d_in, const int* in_sizes, int n_in,
                              void* d_out, int out_size, void* d_ws, size_t ws_size,
                              hipStream_t stream) {
    (void)in_sizes; (void)n_in; (void)out_size;
    const float* feature = (const float*)d_in[0];
    const float* cls_w   = (const float*)d_in[1];
    const float* cls_b   = (const float*)d_in[2];
    const float* box_w   = (const float*)d_in[3];
    const float* box_b   = (const float*)d_in[4];
    const float* score_w = (const float*)d_in[5];
    const float* score_b = (const float*)d_in[6];
    const float* pred_w  = (const float*)d_in[7];
    const float* pred_b  = (const float*)d_in[8];
    const float* ctn_w   = (const float*)d_in[9];
    const float* ctn_b   = (const float*)d_in[10];
    const float* conf_w1 = (const float*)d_in[11];
    const float* conf_b1 = (const float*)d_in[12];
    const float* conf_w2 = (const float*)d_in[13];
    const float* conf_b2 = (const float*)d_in[14];

    float* out      = (float*)d_out;
    float* pred_cls = out;
    float* pred_reg = out + NPIX;
    float* pred_ctn = out + NPIX + (size_t)NPIX*64;

    char* ws = (char*)d_ws;
    size_t off = 0;
    auto alloc = [&](size_t b){ size_t rr = off; off += (b + 255) & ~(size_t)255; return rr; };
    u16* aA = (u16*)(ws + alloc(ACT_BYTES));
    u16* aB = (u16*)(ws + alloc(ACT_BYTES));
    const size_t TWR = (size_t)4*9*256*256;   // tower wt elements
    const size_t HDW = (size_t)9*128*256;     // head wt elements
    u16* wCls = (u16*)(ws + alloc(TWR*2));
    u16* wBox = (u16*)(ws + alloc(TWR*2));
    u16* wSc  = (u16*)(ws + alloc(HDW*2));
    u16* wPc  = (u16*)(ws + alloc(HDW*2));
    float* bPc = (float*)(ws + alloc(128*4));
    float* bSc = (float*)(ws + alloc(128*4));
    float* clsScore = (float*)(ws + alloc((size_t)NPIX*4));
    if (ws_size < off) return;   // insufficient workspace: bail (bench will flag)

    dim3 B(256);
    // prep
    zero_borders<<<508, B, 0, stream>>>(aA, aB);
    wt_tower<<<9216, B, 0, stream>>>(cls_w, wCls);
    wt_tower<<<9216, B, 0, stream>>>(box_w, wBox);
    wt_score<<<1152, B, 0, stream>>>(score_w, wSc);
    wt_predctn<<<1152, B, 0, stream>>>(pred_w, ctn_w, wPc);
    prep_bias<<<1, 128, 0, stream>>>(pred_b, ctn_b, score_b, bPc, bSc);

    const size_t LW = (size_t)9*256*256;      // per-layer tower wt elements
    // cls tower: feat->A, A->B->A->B->A  (B is clobbered along the way — box tower
    // re-materializes its own input below; do NOT share the feature copy)
    feat2act<<<9600, B, 0, stream>>>(feature, aA);
    conv3x3_k<0><<<2000, B, 0, stream>>>(aA, wCls+0*LW, cls_b+0*256, aB, nullptr, nullptr, 2, 256);
    conv3x3_k<0><<<2000, B, 0, stream>>>(aB, wCls+1*LW, cls_b+1*256, aA, nullptr, nullptr, 2, 256);
    conv3x3_k<0><<<2000, B, 0, stream>>>(aA, wCls+2*LW, cls_b+2*256, aB, nullptr, nullptr, 2, 256);
    conv3x3_k<0><<<2000, B, 0, stream>>>(aB, wCls+3*LW, cls_b+3*256, aA, nullptr, nullptr, 2, 256);
    // score head (reads x4 in A)
    conv3x3_k<2><<<1000, B, 0, stream>>>(aA, wSc, bSc, nullptr, clsScore, nullptr, 1, 128);
    // box tower: feat->B, B->A->B->A->B
    feat2act<<<9600, B, 0, stream>>>(feature, aB);
    conv3x3_k<0><<<2000, B, 0, stream>>>(aB, wBox+0*LW, box_b+0*256, aA, nullptr, nullptr, 2, 256);
    conv3x3_k<0><<<2000, B, 0, stream>>>(aA, wBox+1*LW, box_b+1*256, aB, nullptr, nullptr, 2, 256);
    conv3x3_k<0><<<2000, B, 0, stream>>>(aB, wBox+2*LW, box_b+2*256, aA, nullptr, nullptr, 2, 256);
    conv3x3_k<0><<<2000, B, 0, stream>>>(aA, wBox+3*LW, box_b+3*256, aB, nullptr, nullptr, 2, 256);
    // pred + ctn head (reads y4 in B) -> writes pred_reg / pred_ctn directly
    conv3x3_k<1><<<1000, B, 0, stream>>>(aB, wPc, bPc, nullptr, pred_reg, pred_ctn, 1, 128);
    // fused stat + conf + final cls
    fuse_stat<<<475, B, 0, stream>>>(pred_reg, clsScore, conf_w1, conf_b1, conf_w2, conf_b2, pred_cls);
}